// Round 1
// 785.293 us; speedup vs baseline: 2.1341x; 2.1341x over previous
//
#include <hip/hip_runtime.h>

typedef float f4 __attribute__((ext_vector_type(4)));

namespace {
constexpr int B = 16;
constexpr int C = 16;
}

// ---------------------------------------------------------------------------
// Pass 1: transpose a chunk of batches from channel-major img[bb][c][y][x]
// to channels-last ws[bb][y][x][c]. Coalesced reads (lane = consecutive x),
// each thread writes its own dense 64B pixel block.
// ---------------------------------------------------------------------------
template <int S>
__global__ __launch_bounds__(256) void transpose_kernel(
    const float* __restrict__ img, float* __restrict__ ws, int total)
{
    constexpr int SS = S * S;
    int idx = blockIdx.x * 256 + threadIdx.x;
    if (idx >= total) return;
    const int bb  = idx / SS;
    const int rem = idx - bb * SS;

    const float* ip = img + (size_t)bb * C * SS + rem;
    float v[C];
#pragma unroll
    for (int c = 0; c < C; ++c) v[c] = ip[(size_t)c * SS];

    f4* op = (f4*)(ws + (size_t)idx * C);
#pragma unroll
    for (int k = 0; k < C / 4; ++k) {
        f4 t = { v[4 * k + 0], v[4 * k + 1], v[4 * k + 2], v[4 * k + 3] };
        op[k] = t;
    }
}

// ---------------------------------------------------------------------------
// Pass 2: gather. One thread = one output pixel, all 16 channels.
// Each tap = one fully-used 64B block (4x float4). Rows with zero weight are
// skipped entirely (exec-masked lanes issue no memory requests).
// ---------------------------------------------------------------------------
template <int S>
__global__ __launch_bounds__(256) void gather_kernel(
    const float* __restrict__ ws, const float* __restrict__ flow,
    float* __restrict__ out, int total)
{
    constexpr int SS = S * S;
    int idx = blockIdx.x * 256 + threadIdx.x;
    if (idx >= total) return;
    const int bb  = idx / SS;
    const int rem = idx - bb * SS;
    const int i   = rem / S;
    const int j   = rem - i * S;

    const float f0 = flow[(size_t)bb * 2 * SS + rem];       // channel 0
    const float f1 = flow[(size_t)bb * 2 * SS + SS + rem];  // channel 1

    const float sm1 = (float)(S - 1);
    // identical op order to the verified kernel (incl. the (i-1) offset)
    const float gx = -1.0f + ((float)i - 1.0f) / sm1 * 2.0f + f0;
    const float gy = -1.0f + ((float)j - 1.0f) / sm1 * 2.0f + f1;
    const float x = (gx + 1.0f) * 0.5f * sm1;
    const float y = (gy + 1.0f) * 0.5f * sm1;

    const float x0f = floorf(x), y0f = floorf(y);
    const float x1f = x0f + 1.0f, y1f = y0f + 1.0f;
    const float wx1 = x - x0f, wx0 = 1.0f - wx1;
    const float wy1 = y - y0f, wy0 = 1.0f - wy1;

    const bool bx0 = (x0f >= 0.0f) && (x0f <= sm1);
    const bool bx1 = (x1f >= 0.0f) && (x1f <= sm1);
    const bool by0 = (y0f >= 0.0f) && (y0f <= sm1);
    const bool by1 = (y1f >= 0.0f) && (y1f <= sm1);

    const int xc0 = (int)fminf(fmaxf(x0f, 0.0f), sm1);
    const int xc1 = (int)fminf(fmaxf(x1f, 0.0f), sm1);
    const int yc0 = (int)fminf(fmaxf(y0f, 0.0f), sm1);
    const int yc1 = (int)fminf(fmaxf(y1f, 0.0f), sm1);

    const float w00 = (by0 && bx0) ? wy0 * wx0 : 0.0f;
    const float w01 = (by0 && bx1) ? wy0 * wx1 : 0.0f;
    const float w10 = (by1 && bx0) ? wy1 * wx0 : 0.0f;
    const float w11 = (by1 && bx1) ? wy1 * wx1 : 0.0f;

    f4 a0 = {0.f, 0.f, 0.f, 0.f};
    f4 a1 = a0, a2 = a0, a3 = a0;

    const float* base = ws + (size_t)bb * SS * C;

    if (w00 != 0.0f || w01 != 0.0f) {           // top row pair (128B contiguous)
        const f4* p0 = (const f4*)(base + (size_t)(yc0 * S + xc0) * C);
        const f4* p1 = (const f4*)(base + (size_t)(yc0 * S + xc1) * C);
        a0 += w00 * p0[0] + w01 * p1[0];
        a1 += w00 * p0[1] + w01 * p1[1];
        a2 += w00 * p0[2] + w01 * p1[2];
        a3 += w00 * p0[3] + w01 * p1[3];
    }
    if (w10 != 0.0f || w11 != 0.0f) {           // bottom row pair
        const f4* p0 = (const f4*)(base + (size_t)(yc1 * S + xc0) * C);
        const f4* p1 = (const f4*)(base + (size_t)(yc1 * S + xc1) * C);
        a0 += w10 * p0[0] + w11 * p1[0];
        a1 += w10 * p0[1] + w11 * p1[1];
        a2 += w10 * p0[2] + w11 * p1[2];
        a3 += w10 * p0[3] + w11 * p1[3];
    }

    float* ob = out + (size_t)bb * C * SS + rem;
    f4 acc[4] = { a0, a1, a2, a3 };
#pragma unroll
    for (int k = 0; k < 4; ++k) {
#pragma unroll
        for (int e = 0; e < 4; ++e) {
            // out is never re-read: bypass L2 allocation, keep it for gathers
            __builtin_nontemporal_store(acc[k][e], &ob[(size_t)(k * 4 + e) * SS]);
        }
    }
}

// ---------------------------------------------------------------------------
// Fallback (ws too small): original fused kernel + zero-weight full skip.
// ---------------------------------------------------------------------------
template <int S>
__global__ __launch_bounds__(256) void warp_fallback(
    const float* __restrict__ img, const float* __restrict__ flow,
    float* __restrict__ out, int total)
{
    constexpr int SS = S * S;
    int idx = blockIdx.x * 256 + threadIdx.x;
    if (idx >= total) return;
    const int b   = idx / SS;
    const int rem = idx - b * SS;
    const int i   = rem / S;
    const int j   = rem - i * S;

    const float f0 = flow[(size_t)b * 2 * SS + rem];
    const float f1 = flow[(size_t)b * 2 * SS + SS + rem];

    const float sm1 = (float)(S - 1);
    const float gx = -1.0f + ((float)i - 1.0f) / sm1 * 2.0f + f0;
    const float gy = -1.0f + ((float)j - 1.0f) / sm1 * 2.0f + f1;
    const float x = (gx + 1.0f) * 0.5f * sm1;
    const float y = (gy + 1.0f) * 0.5f * sm1;

    const float x0f = floorf(x), y0f = floorf(y);
    const float x1f = x0f + 1.0f, y1f = y0f + 1.0f;
    const float wx1 = x - x0f, wx0 = 1.0f - wx1;
    const float wy1 = y - y0f, wy0 = 1.0f - wy1;

    const bool bx0 = (x0f >= 0.0f) && (x0f <= sm1);
    const bool bx1 = (x1f >= 0.0f) && (x1f <= sm1);
    const bool by0 = (y0f >= 0.0f) && (y0f <= sm1);
    const bool by1 = (y1f >= 0.0f) && (y1f <= sm1);

    const int xc0 = (int)fminf(fmaxf(x0f, 0.0f), sm1);
    const int xc1 = (int)fminf(fmaxf(x1f, 0.0f), sm1);
    const int yc0 = (int)fminf(fmaxf(y0f, 0.0f), sm1);
    const int yc1 = (int)fminf(fmaxf(y1f, 0.0f), sm1);

    const float w00 = (by0 && bx0) ? wy0 * wx0 : 0.0f;
    const float w01 = (by0 && bx1) ? wy0 * wx1 : 0.0f;
    const float w10 = (by1 && bx0) ? wy1 * wx0 : 0.0f;
    const float w11 = (by1 && bx1) ? wy1 * wx1 : 0.0f;

    const int o00 = yc0 * S + xc0;
    const int o01 = yc0 * S + xc1;
    const int o10 = yc1 * S + xc0;
    const int o11 = yc1 * S + xc1;

    const float* ib = img + (size_t)b * C * SS;
    float*       ob = out + (size_t)b * C * SS + rem;

    if (w00 + w01 + w10 + w11 != 0.0f) {
#pragma unroll 4
        for (int c = 0; c < C; ++c) {
            const float* p = ib + (size_t)c * SS;
            ob[(size_t)c * SS] =
                w00 * p[o00] + w01 * p[o01] + w10 * p[o10] + w11 * p[o11];
        }
    } else {
#pragma unroll 4
        for (int c = 0; c < C; ++c) ob[(size_t)c * SS] = 0.0f;
    }
}

// ---------------------------------------------------------------------------
template <int S>
static void run_scale(const float* img, const float* flow, float* out,
                      float* ws, size_t ws_size, hipStream_t stream)
{
    constexpr int SS = S * S;
    const size_t per_b = (size_t)SS * C * sizeof(float);
    int chunk = (ws == nullptr) ? 0 : (int)(ws_size / per_b);
    if (chunk > B) chunk = B;

    if (chunk >= 1) {
        for (int b0 = 0; b0 < B; b0 += chunk) {
            const int nb    = (b0 + chunk <= B) ? chunk : (B - b0);
            const int total = nb * SS;
            const int grid  = (total + 255) / 256;
            transpose_kernel<S><<<grid, 256, 0, stream>>>(
                img + (size_t)b0 * C * SS, ws, total);
            gather_kernel<S><<<grid, 256, 0, stream>>>(
                ws, flow + (size_t)b0 * 2 * SS,
                out + (size_t)b0 * C * SS, total);
        }
    } else {
        const int total = B * SS;
        warp_fallback<S><<<(total + 255) / 256, 256, 0, stream>>>(
            img, flow, out, total);
    }
}

extern "C" void kernel_launch(void* const* d_in, const int* /*in_sizes*/, int /*n_in*/,
                              void* d_out, int /*out_size*/, void* d_ws, size_t ws_size,
                              hipStream_t stream)
{
    float* out = (float*)d_out;
    float* ws  = (float*)d_ws;

    run_scale<512>((const float*)d_in[0], (const float*)d_in[1], out, ws, ws_size, stream);
    out += (size_t)B * C * 512 * 512;
    run_scale<256>((const float*)d_in[2], (const float*)d_in[3], out, ws, ws_size, stream);
    out += (size_t)B * C * 256 * 256;
    run_scale<128>((const float*)d_in[4], (const float*)d_in[5], out, ws, ws_size, stream);
    out += (size_t)B * C * 128 * 128;
    run_scale<64>((const float*)d_in[6], (const float*)d_in[7], out, ws, ws_size, stream);
}